// Round 1
// baseline (540.879 us; speedup 1.0000x reference)
//
#include <hip/hip_runtime.h>
#include <cstdint>
#include <cstddef>

#define DEV __device__ __forceinline__

typedef __bf16 bf16x8 __attribute__((ext_vector_type(8)));
typedef float f32x4 __attribute__((ext_vector_type(4)));

DEV unsigned short f2bf(float f) {
  unsigned u = __builtin_bit_cast(unsigned, f);
  u += 0x7fffu + ((u >> 16) & 1u);   // RNE
  return (unsigned short)(u >> 16);
}
DEV float bf2f(unsigned short h) {
  return __builtin_bit_cast(float, (unsigned)h << 16);
}

// ---------------- concat [x | event] -> bf16 A-matrix [8192 x 1088] ----------------
__global__ __launch_bounds__(256)
void k_concat(const float* __restrict__ x, const float* __restrict__ ev,
              unsigned short* __restrict__ Aaug) {
  int col4 = blockIdx.x * 256 + threadIdx.x;      // float4 index within row, 272 total
  if (col4 >= 272) return;
  size_t row = blockIdx.y;
  float4 v = (col4 < 256) ? reinterpret_cast<const float4*>(x + row * 1024)[col4]
                          : reinterpret_cast<const float4*>(ev + row * 64)[col4 - 256];
  ushort4 o; o.x = f2bf(v.x); o.y = f2bf(v.y); o.z = f2bf(v.z); o.w = f2bf(v.w);
  reinterpret_cast<ushort4*>(Aaug + row * 1088)[col4] = o;
}

// ---------------- tiled transpose fp32[R,C] -> bf16[Cout,R] (pad rows C..Cout with 0) ----------------
__global__ void k_transpose(const float* __restrict__ in, unsigned short* __restrict__ out,
                            int R, int C, int Cout) {
  __shared__ float tile[32][33];
  int c0 = blockIdx.x * 32, r0 = blockIdx.y * 32;
  int tx = threadIdx.x, ty = threadIdx.y;   // block (32,8)
#pragma unroll
  for (int i = 0; i < 4; ++i) {
    int r = r0 + ty + i * 8, c = c0 + tx;
    tile[ty + i * 8][tx] = (r < R && c < C) ? in[(size_t)r * C + c] : 0.f;
  }
  __syncthreads();
#pragma unroll
  for (int i = 0; i < 4; ++i) {
    int c = c0 + ty + i * 8, r = r0 + tx;
    if (c < Cout && r < R) out[(size_t)c * R + r] = f2bf(tile[tx][ty + i * 8]);
  }
}

// ---------------- 128x128 MFMA GEMM, A[M,K] bf16 row-major, Bt[N,K] bf16 row-major ----------------
// EPI 0: outF = acc + bias[col]                 (aug)
// EPI 1: split halves -> outB1 / outB2 bf16     (xh | z)
// EPI 2: outB1 bf16, ld = N                     (dbl)
// EPI 3: outF = softplus(acc + bias[col])       (dt)
// EPI 4: outF = resid + acc                     (final out)
template <int EPI>
__global__ __launch_bounds__(256)
void k_gemm(const unsigned short* __restrict__ A, const unsigned short* __restrict__ Bt,
            int N, int K, int lda, int ldb,
            float* __restrict__ outF, unsigned short* __restrict__ outB1,
            unsigned short* __restrict__ outB2,
            const float* __restrict__ bias, const float* __restrict__ resid) {
  __shared__ alignas(16) unsigned short sA[128 * 64];
  __shared__ alignas(16) unsigned short sB[128 * 64];
  int tid = threadIdx.x;
  int lane = tid & 63, w = tid >> 6;
  // XCD-aware swizzle (all grids are multiples of 8 blocks)
  int nbx = gridDim.x;
  int nwg = nbx * gridDim.y;
  int orig = blockIdx.y * nbx + blockIdx.x;
  int swz = (orig & 7) * (nwg >> 3) + (orig >> 3);
  int brow = swz / nbx, bcol = swz % nbx;
  size_t row0 = (size_t)brow * 128, col0 = (size_t)bcol * 128;

  int lrow_s = tid >> 3;   // staging row 0..31 (+32 per round)
  int g_s = tid & 7;       // staging 16B granule within row
  int wrow = (w >> 1) * 64, wcol = (w & 1) * 64;
  int frow = lane & 15, fk = lane >> 4;
  f32x4 acc[4][4] = {};

  for (int kt = 0; kt < K; kt += 64) {
    __syncthreads();
#pragma unroll
    for (int r = 0; r < 4; ++r) {
      int lr = r * 32 + lrow_s;
      int gs = g_s ^ (lr & 7);  // inverse-swizzled global source, linear LDS dest
      const unsigned short* srcA = A + (size_t)(row0 + lr) * lda + kt + gs * 8;
      const unsigned short* srcB = Bt + (size_t)(col0 + lr) * ldb + kt + gs * 8;
      unsigned short* dstA = sA + (r * 32 + w * 8) * 64;
      unsigned short* dstB = sB + (r * 32 + w * 8) * 64;
      __builtin_amdgcn_global_load_lds(srcA, dstA, 16, 0, 0);
      __builtin_amdgcn_global_load_lds(srcB, dstB, 16, 0, 0);
    }
    __syncthreads();
#pragma unroll
    for (int kw = 0; kw < 2; ++kw) {
      bf16x8 af[4], bfr[4];
      int gk = kw * 4 + fk;
#pragma unroll
      for (int mi = 0; mi < 4; ++mi) {
        int rr = wrow + mi * 16 + frow;
        af[mi] = *reinterpret_cast<const bf16x8*>(sA + rr * 64 + ((gk ^ (rr & 7)) * 8));
      }
#pragma unroll
      for (int ni = 0; ni < 4; ++ni) {
        int rr = wcol + ni * 16 + frow;
        bfr[ni] = *reinterpret_cast<const bf16x8*>(sB + rr * 64 + ((gk ^ (rr & 7)) * 8));
      }
#pragma unroll
      for (int mi = 0; mi < 4; ++mi)
#pragma unroll
        for (int ni = 0; ni < 4; ++ni)
          acc[mi][ni] = __builtin_amdgcn_mfma_f32_16x16x32_bf16(af[mi], bfr[ni], acc[mi][ni], 0, 0, 0);
    }
  }

#pragma unroll
  for (int mi = 0; mi < 4; ++mi) {
#pragma unroll
    for (int ni = 0; ni < 4; ++ni) {
#pragma unroll
      for (int r = 0; r < 4; ++r) {
        size_t row = row0 + wrow + mi * 16 + fk * 4 + r;
        size_t col = col0 + wcol + ni * 16 + frow;
        float v = acc[mi][ni][r];
        if constexpr (EPI == 0) {
          outF[row * N + col] = v + bias[col];
        } else if constexpr (EPI == 1) {
          int hn = N >> 1;
          if ((int)col < hn) outB1[row * hn + col] = f2bf(v);
          else               outB2[row * hn + (col - hn)] = f2bf(v);
        } else if constexpr (EPI == 2) {
          outB1[row * N + col] = f2bf(v);
        } else if constexpr (EPI == 3) {
          float xx = v + bias[col];
          float sp = (xx > 15.f) ? xx : __logf(1.f + __expf(xx));
          outF[row * N + col] = sp;
        } else {
          outF[row * N + col] = resid[row * N + col] + v;
        }
      }
    }
  }
}

// ---------------- LayerNorm over D=1024, fp32 in -> bf16 out ----------------
__global__ __launch_bounds__(256)
void k_ln(const float* __restrict__ aug, const float* __restrict__ gam,
          const float* __restrict__ bet, unsigned short* __restrict__ h) {
  int tid = threadIdx.x;
  size_t row = blockIdx.x;
  float4 v = reinterpret_cast<const float4*>(aug + row * 1024)[tid];
  float s = v.x + v.y + v.z + v.w;
  float ss = v.x * v.x + v.y * v.y + v.z * v.z + v.w * v.w;
#pragma unroll
  for (int m = 32; m >= 1; m >>= 1) {
    s += __shfl_xor(s, m, 64);
    ss += __shfl_xor(ss, m, 64);
  }
  __shared__ float rb[8];
  if ((tid & 63) == 0) { rb[tid >> 6] = s; rb[4 + (tid >> 6)] = ss; }
  __syncthreads();
  float ts = rb[0] + rb[1] + rb[2] + rb[3];
  float tss = rb[4] + rb[5] + rb[6] + rb[7];
  float mu = ts * (1.f / 1024.f);
  float var = tss * (1.f / 1024.f) - mu * mu;
  float rs = rsqrtf(var + 1e-5f);
  float4 gv = reinterpret_cast<const float4*>(gam)[tid];
  float4 bv = reinterpret_cast<const float4*>(bet)[tid];
  ushort4 o;
  o.x = f2bf((v.x - mu) * rs * gv.x + bv.x);
  o.y = f2bf((v.y - mu) * rs * gv.y + bv.y);
  o.z = f2bf((v.z - mu) * rs * gv.z + bv.z);
  o.w = f2bf((v.w - mu) * rs * gv.w + bv.w);
  reinterpret_cast<ushort4*>(h + row * 1024)[tid] = o;
}

// ---------------- causal depthwise conv (K=4) + SiLU ----------------
__global__ __launch_bounds__(256)
void k_conv(const unsigned short* __restrict__ xh, const float* __restrict__ cw,
            const float* __restrict__ cb, unsigned short* __restrict__ xc) {
  int d = blockIdx.x * 256 + threadIdx.x;     // 2048
  int t = blockIdx.y, b = blockIdx.z;
  size_t rowb = (size_t)b * 2048;             // b*L
  float acc = cb[d];
#pragma unroll
  for (int k = 0; k < 4; ++k) {
    int tt = t - 3 + k;
    if (tt >= 0) acc += cw[d * 4 + k] * bf2f(xh[(rowb + tt) * 2048 + d]);
  }
  float sg = 1.f / (1.f + __expf(-acc));
  xc[(rowb + t) * 2048 + d] = f2bf(acc * sg);
}

// ---------------- chunked selective scan ----------------
// 16 chunks x 128 steps. Pass A (FINAL=false): per-chunk local state S and decay product P.
// Pass C (FINAL=true): init from carried-in state, produce y, fuse +D*u and *silu(z).
template <bool FINAL>
__global__ __launch_bounds__(256)
void k_scan(const float* __restrict__ dt, const unsigned short* __restrict__ xc,
            const unsigned short* __restrict__ dbl, const float* __restrict__ A_log,
            float* __restrict__ S, float* __restrict__ P,
            const float* __restrict__ Hin, const float* __restrict__ Dp,
            const unsigned short* __restrict__ z, unsigned short* __restrict__ yg) {
  int d = blockIdx.x * 256 + threadIdx.x;
  int b = blockIdx.y, c = blockIdx.z;
  int t0 = c * 128;
  size_t hoff = (((size_t)c * 4 + b) * 2048 + d) * 16;
  float An[16], h[16], p[16];
#pragma unroll
  for (int n = 0; n < 16; ++n) {
    An[n] = -__expf(A_log[(size_t)d * 16 + n]);
    h[n] = FINAL ? Hin[hoff + n] : 0.f;
    p[n] = 1.f;
  }
  float Dv = FINAL ? Dp[d] : 0.f;
  __shared__ float sBC[64][32];
  for (int sc = 0; sc < 2; ++sc) {
    __syncthreads();
    {
      int s = threadIdx.x >> 2, j8 = (threadIdx.x & 3) * 8;
      size_t rowg = (size_t)b * 2048 + t0 + sc * 64 + s;
      uint4 raw = *reinterpret_cast<const uint4*>(dbl + rowg * 128 + 64 + j8);
      unsigned rr4[4] = {raw.x, raw.y, raw.z, raw.w};
#pragma unroll
      for (int q = 0; q < 4; ++q) {
        sBC[s][j8 + 2 * q]     = bf2f((unsigned short)(rr4[q] & 0xffffu));
        sBC[s][j8 + 2 * q + 1] = bf2f((unsigned short)(rr4[q] >> 16));
      }
    }
    __syncthreads();
    for (int si = 0; si < 64; ++si) {
      int t = t0 + sc * 64 + si;
      size_t rr = ((size_t)b * 2048 + t) * 2048 + d;
      float dtv = dt[rr];
      float uv = bf2f(xc[rr]);
      float dtu = dtv * uv;
      float y = 0.f;
#pragma unroll
      for (int n = 0; n < 16; ++n) {
        float a = __expf(dtv * An[n]);
        h[n] = a * h[n] + dtu * sBC[si][n];
        if constexpr (!FINAL) p[n] *= a;
        if constexpr (FINAL) y += h[n] * sBC[si][16 + n];
      }
      if constexpr (FINAL) {
        float zv = bf2f(z[rr]);
        float sig = 1.f / (1.f + __expf(-zv));
        yg[rr] = f2bf((y + Dv * uv) * (zv * sig));
      }
    }
  }
  if constexpr (!FINAL) {
#pragma unroll
    for (int n = 0; n < 16; ++n) { S[hoff + n] = h[n]; P[hoff + n] = p[n]; }
  }
}

// combine chunk boundaries: Hin[c] = state entering chunk c
__global__ __launch_bounds__(256)
void k_scanB(const float* __restrict__ S, const float* __restrict__ P, float* __restrict__ Hin) {
  int id = blockIdx.x * 256 + threadIdx.x;   // 8192 = B*DI
  int b = id >> 11, d = id & 2047;
  float h[16];
#pragma unroll
  for (int n = 0; n < 16; ++n) h[n] = 0.f;
  for (int c = 0; c < 16; ++c) {
    size_t o = (((size_t)c * 4 + b) * 2048 + d) * 16;
#pragma unroll
    for (int n = 0; n < 16; ++n) {
      Hin[o + n] = h[n];
      h[n] = S[o + n] + P[o + n] * h[n];
    }
  }
}

extern "C" void kernel_launch(void* const* d_in, const int* in_sizes, int n_in,
                              void* d_out, int out_size, void* d_ws, size_t ws_size,
                              hipStream_t stream) {
  const float* x       = (const float*)d_in[0];
  const float* ev      = (const float*)d_in[1];
  const float* W_in    = (const float*)d_in[2];
  const float* b_in    = (const float*)d_in[3];
  const float* ln_g    = (const float*)d_in[4];
  const float* ln_b    = (const float*)d_in[5];
  const float* in_proj = (const float*)d_in[6];
  const float* conv_w  = (const float*)d_in[7];
  const float* conv_b  = (const float*)d_in[8];
  const float* x_proj  = (const float*)d_in[9];
  const float* dt_proj = (const float*)d_in[10];
  const float* dt_b    = (const float*)d_in[11];
  const float* A_log   = (const float*)d_in[12];
  const float* D_par   = (const float*)d_in[13];
  const float* out_w   = (const float*)d_in[14];
  float* out = (float*)d_out;

  char* ws = (char*)d_ws;
  size_t off = 0;
  auto alloc = [&](size_t bytes) {
    char* p = ws + off;
    off = (off + bytes + 255) & ~(size_t)255;
    return p;
  };
  float* aug           = (float*)alloc(8192ull * 1024 * 4);   // residual, fp32
  float* dtf           = (float*)alloc(8192ull * 2048 * 4);   // dt after softplus, fp32
  unsigned short* Aaug = (unsigned short*)alloc(8192ull * 1088 * 2);
  unsigned short* WinT = (unsigned short*)alloc(1024ull * 1088 * 2);
  unsigned short* ipT  = (unsigned short*)alloc(4096ull * 1024 * 2);
  unsigned short* xpT  = (unsigned short*)alloc(128ull * 2048 * 2);
  unsigned short* dpT  = (unsigned short*)alloc(2048ull * 64 * 2);
  unsigned short* opT  = (unsigned short*)alloc(1024ull * 2048 * 2);
  unsigned short* xh   = (unsigned short*)alloc(8192ull * 2048 * 2);
  unsigned short* zb   = (unsigned short*)alloc(8192ull * 2048 * 2);
  unsigned short* xcb  = (unsigned short*)alloc(8192ull * 2048 * 2);
  unsigned short* dbl  = (unsigned short*)alloc(8192ull * 128 * 2);
  float* Sb  = (float*)alloc(16ull * 4 * 2048 * 16 * 4);
  float* Pb  = (float*)alloc(16ull * 4 * 2048 * 16 * 4);
  float* Hin = (float*)alloc(16ull * 4 * 2048 * 16 * 4);
  unsigned short* hb = Aaug;  // LN output aliases Aaug (consumed by gemm<0> before k_ln)
  unsigned short* yg = xh;    // gated y aliases xh (consumed by k_conv before scan C)

  k_concat<<<dim3(2, 8192), 256, 0, stream>>>(x, ev, Aaug);
  k_transpose<<<dim3(32, 34), dim3(32, 8), 0, stream>>>(W_in, WinT, 1088, 1024, 1024);
  k_transpose<<<dim3(128, 32), dim3(32, 8), 0, stream>>>(in_proj, ipT, 1024, 4096, 4096);
  k_transpose<<<dim3(4, 64), dim3(32, 8), 0, stream>>>(x_proj, xpT, 2048, 96, 128);
  k_transpose<<<dim3(64, 2), dim3(32, 8), 0, stream>>>(dt_proj, dpT, 64, 2048, 2048);
  k_transpose<<<dim3(32, 64), dim3(32, 8), 0, stream>>>(out_w, opT, 2048, 1024, 1024);

  // aug = [x|ev] @ W_in + b_in   (fp32 out, residual)
  k_gemm<0><<<dim3(8, 64), 256, 0, stream>>>(Aaug, WinT, 1024, 1088, 1088, 1088,
                                             aug, nullptr, nullptr, b_in, nullptr);
  k_ln<<<dim3(8192), 256, 0, stream>>>(aug, ln_g, ln_b, hb);
  // xz = h @ in_proj -> xh | z
  k_gemm<1><<<dim3(32, 64), 256, 0, stream>>>(hb, ipT, 4096, 1024, 1024, 1024,
                                              nullptr, xh, zb, nullptr, nullptr);
  k_conv<<<dim3(8, 2048, 4), 256, 0, stream>>>(xh, conv_w, conv_b, xcb);
  // dbl = xc @ x_proj (N padded 96->128)
  k_gemm<2><<<dim3(1, 64), 256, 0, stream>>>(xcb, xpT, 128, 2048, 2048, 2048,
                                             nullptr, dbl, nullptr, nullptr, nullptr);
  // dt = softplus(dbl[:, :64] @ dt_proj + b)
  k_gemm<3><<<dim3(16, 64), 256, 0, stream>>>(dbl, dpT, 2048, 64, 128, 64,
                                              dtf, nullptr, nullptr, dt_b, nullptr);
  k_scan<false><<<dim3(8, 4, 16), 256, 0, stream>>>(dtf, xcb, dbl, A_log, Sb, Pb,
                                                    nullptr, nullptr, nullptr, nullptr);
  k_scanB<<<dim3(32), 256, 0, stream>>>(Sb, Pb, Hin);
  k_scan<true><<<dim3(8, 4, 16), 256, 0, stream>>>(dtf, xcb, dbl, A_log, nullptr, nullptr,
                                                   Hin, D_par, zb, yg);
  // out = residual + yg @ out_proj
  k_gemm<4><<<dim3(8, 64), 256, 0, stream>>>(yg, opT, 1024, 2048, 2048, 2048,
                                             out, nullptr, nullptr, nullptr, aug);
}

// Round 2
// 468.486 us; speedup vs baseline: 1.1545x; 1.1545x over previous
//
#include <hip/hip_runtime.h>
#include <cstdint>
#include <cstddef>

#define DEV __device__ __forceinline__

typedef __bf16 bf16x8 __attribute__((ext_vector_type(8)));
typedef float f32x4 __attribute__((ext_vector_type(4)));

DEV unsigned short f2bf(float f) {
  unsigned u = __builtin_bit_cast(unsigned, f);
  u += 0x7fffu + ((u >> 16) & 1u);   // RNE
  return (unsigned short)(u >> 16);
}
DEV float bf2f(unsigned short h) {
  return __builtin_bit_cast(float, (unsigned)h << 16);
}

// ---------------- concat [x | event] -> bf16 A-matrix [8192 x 1088] ----------------
__global__ __launch_bounds__(256)
void k_concat(const float* __restrict__ x, const float* __restrict__ ev,
              unsigned short* __restrict__ Aaug) {
  int col4 = blockIdx.x * 256 + threadIdx.x;      // float4 index within row, 272 total
  if (col4 >= 272) return;
  size_t row = blockIdx.y;
  float4 v = (col4 < 256) ? reinterpret_cast<const float4*>(x + row * 1024)[col4]
                          : reinterpret_cast<const float4*>(ev + row * 64)[col4 - 256];
  ushort4 o; o.x = f2bf(v.x); o.y = f2bf(v.y); o.z = f2bf(v.z); o.w = f2bf(v.w);
  reinterpret_cast<ushort4*>(Aaug + row * 1088)[col4] = o;
}

// ---------------- tiled transpose fp32[R,C] -> bf16[Cout,R] (pad rows C..Cout with 0) ----------------
__global__ void k_transpose(const float* __restrict__ in, unsigned short* __restrict__ out,
                            int R, int C, int Cout) {
  __shared__ float tile[32][33];
  int c0 = blockIdx.x * 32, r0 = blockIdx.y * 32;
  int tx = threadIdx.x, ty = threadIdx.y;   // block (32,8)
#pragma unroll
  for (int i = 0; i < 4; ++i) {
    int r = r0 + ty + i * 8, c = c0 + tx;
    tile[ty + i * 8][tx] = (r < R && c < C) ? in[(size_t)r * C + c] : 0.f;
  }
  __syncthreads();
#pragma unroll
  for (int i = 0; i < 4; ++i) {
    int c = c0 + ty + i * 8, r = r0 + tx;
    if (c < Cout && r < R) out[(size_t)c * R + r] = f2bf(tile[tx][ty + i * 8]);
  }
}

// ---------------- 128x128 MFMA GEMM, A[M,K] bf16 row-major, Bt[N,K] bf16 row-major ----------------
// EPI 0: outF = acc + bias[col]                 (aug)
// EPI 1: split halves -> outB1 / outB2 bf16     (xh | z)
// EPI 2: outB1 bf16, ld = N                     (dbl)
// EPI 3: outF = softplus(acc + bias[col])       (dt)
// EPI 4: outF = resid + acc                     (final out)
template <int EPI>
__global__ __launch_bounds__(256)
void k_gemm(const unsigned short* __restrict__ A, const unsigned short* __restrict__ Bt,
            int N, int K, int lda, int ldb,
            float* __restrict__ outF, unsigned short* __restrict__ outB1,
            unsigned short* __restrict__ outB2,
            const float* __restrict__ bias, const float* __restrict__ resid) {
  __shared__ alignas(16) unsigned short sA[128 * 64];
  __shared__ alignas(16) unsigned short sB[128 * 64];
  int tid = threadIdx.x;
  int lane = tid & 63, w = tid >> 6;
  // XCD-aware swizzle (all grids are multiples of 8 blocks)
  int nbx = gridDim.x;
  int nwg = nbx * gridDim.y;
  int orig = blockIdx.y * nbx + blockIdx.x;
  int swz = (orig & 7) * (nwg >> 3) + (orig >> 3);
  int brow = swz / nbx, bcol = swz % nbx;
  size_t row0 = (size_t)brow * 128, col0 = (size_t)bcol * 128;

  int lrow_s = tid >> 3;   // staging row 0..31 (+32 per round)
  int g_s = tid & 7;       // staging 16B granule within row
  int wrow = (w >> 1) * 64, wcol = (w & 1) * 64;
  int frow = lane & 15, fk = lane >> 4;
  f32x4 acc[4][4] = {};

  for (int kt = 0; kt < K; kt += 64) {
    __syncthreads();
#pragma unroll
    for (int r = 0; r < 4; ++r) {
      int lr = r * 32 + lrow_s;
      int gs = g_s ^ (lr & 7);  // inverse-swizzled global source, linear LDS dest
      const unsigned short* srcA = A + (size_t)(row0 + lr) * lda + kt + gs * 8;
      const unsigned short* srcB = Bt + (size_t)(col0 + lr) * ldb + kt + gs * 8;
      unsigned short* dstA = sA + (r * 32 + w * 8) * 64;
      unsigned short* dstB = sB + (r * 32 + w * 8) * 64;
      __builtin_amdgcn_global_load_lds(srcA, dstA, 16, 0, 0);
      __builtin_amdgcn_global_load_lds(srcB, dstB, 16, 0, 0);
    }
    __syncthreads();
#pragma unroll
    for (int kw = 0; kw < 2; ++kw) {
      bf16x8 af[4], bfr[4];
      int gk = kw * 4 + fk;
#pragma unroll
      for (int mi = 0; mi < 4; ++mi) {
        int rr = wrow + mi * 16 + frow;
        af[mi] = *reinterpret_cast<const bf16x8*>(sA + rr * 64 + ((gk ^ (rr & 7)) * 8));
      }
#pragma unroll
      for (int ni = 0; ni < 4; ++ni) {
        int rr = wcol + ni * 16 + frow;
        bfr[ni] = *reinterpret_cast<const bf16x8*>(sB + rr * 64 + ((gk ^ (rr & 7)) * 8));
      }
#pragma unroll
      for (int mi = 0; mi < 4; ++mi)
#pragma unroll
        for (int ni = 0; ni < 4; ++ni)
          acc[mi][ni] = __builtin_amdgcn_mfma_f32_16x16x32_bf16(af[mi], bfr[ni], acc[mi][ni], 0, 0, 0);
    }
  }

#pragma unroll
  for (int mi = 0; mi < 4; ++mi) {
#pragma unroll
    for (int ni = 0; ni < 4; ++ni) {
#pragma unroll
      for (int r = 0; r < 4; ++r) {
        size_t row = row0 + wrow + mi * 16 + fk * 4 + r;
        size_t col = col0 + wcol + ni * 16 + frow;
        float v = acc[mi][ni][r];
        if constexpr (EPI == 0) {
          outF[row * N + col] = v + bias[col];
        } else if constexpr (EPI == 1) {
          int hn = N >> 1;
          if ((int)col < hn) outB1[row * hn + col] = f2bf(v);
          else               outB2[row * hn + (col - hn)] = f2bf(v);
        } else if constexpr (EPI == 2) {
          outB1[row * N + col] = f2bf(v);
        } else if constexpr (EPI == 3) {
          float xx = v + bias[col];
          float sp = (xx > 15.f) ? xx : __logf(1.f + __expf(xx));
          outF[row * N + col] = sp;
        } else {
          outF[row * N + col] = resid[row * N + col] + v;
        }
      }
    }
  }
}

// ---------------- LayerNorm over D=1024, fp32 in -> bf16 out ----------------
__global__ __launch_bounds__(256)
void k_ln(const float* __restrict__ aug, const float* __restrict__ gam,
          const float* __restrict__ bet, unsigned short* __restrict__ h) {
  int tid = threadIdx.x;
  size_t row = blockIdx.x;
  float4 v = reinterpret_cast<const float4*>(aug + row * 1024)[tid];
  float s = v.x + v.y + v.z + v.w;
  float ss = v.x * v.x + v.y * v.y + v.z * v.z + v.w * v.w;
#pragma unroll
  for (int m = 32; m >= 1; m >>= 1) {
    s += __shfl_xor(s, m, 64);
    ss += __shfl_xor(ss, m, 64);
  }
  __shared__ float rb[8];
  if ((tid & 63) == 0) { rb[tid >> 6] = s; rb[4 + (tid >> 6)] = ss; }
  __syncthreads();
  float ts = rb[0] + rb[1] + rb[2] + rb[3];
  float tss = rb[4] + rb[5] + rb[6] + rb[7];
  float mu = ts * (1.f / 1024.f);
  float var = tss * (1.f / 1024.f) - mu * mu;
  float rs = rsqrtf(var + 1e-5f);
  float4 gv = reinterpret_cast<const float4*>(gam)[tid];
  float4 bv = reinterpret_cast<const float4*>(bet)[tid];
  ushort4 o;
  o.x = f2bf((v.x - mu) * rs * gv.x + bv.x);
  o.y = f2bf((v.y - mu) * rs * gv.y + bv.y);
  o.z = f2bf((v.z - mu) * rs * gv.z + bv.z);
  o.w = f2bf((v.w - mu) * rs * gv.w + bv.w);
  reinterpret_cast<ushort4*>(h + row * 1024)[tid] = o;
}

// ---------------- causal depthwise conv (K=4) + SiLU ----------------
__global__ __launch_bounds__(256)
void k_conv(const unsigned short* __restrict__ xh, const float* __restrict__ cw,
            const float* __restrict__ cb, unsigned short* __restrict__ xc) {
  int d = blockIdx.x * 256 + threadIdx.x;     // 2048
  int t = blockIdx.y, b = blockIdx.z;
  size_t rowb = (size_t)b * 2048;             // b*L
  float acc = cb[d];
#pragma unroll
  for (int k = 0; k < 4; ++k) {
    int tt = t - 3 + k;
    if (tt >= 0) acc += cw[d * 4 + k] * bf2f(xh[(rowb + tt) * 2048 + d]);
  }
  float sg = 1.f / (1.f + __expf(-acc));
  xc[(rowb + t) * 2048 + d] = f2bf(acc * sg);
}

// ---------------- chunked selective scan: 32 chunks x 64 steps ----------------
// Pass A (FINAL=false): local state S (from h=0) and per-chunk sum of dt (SD).
//   Decay product over chunk = exp(An * sum dt) — recovered in k_scanB, so no P array.
// Pass C (FINAL=true): init from carried-in state Hin, produce y, fuse +D*u and *silu(z).
template <bool FINAL>
__global__ __launch_bounds__(256)
void k_scan(const float* __restrict__ dt, const unsigned short* __restrict__ xc,
            const unsigned short* __restrict__ dbl, const float* __restrict__ A_log,
            float* __restrict__ S, float* __restrict__ SD,
            const float* __restrict__ Hin, const float* __restrict__ Dp,
            const unsigned short* __restrict__ z, unsigned short* __restrict__ yg) {
  int d = blockIdx.x * 256 + threadIdx.x;
  int b = blockIdx.y, c = blockIdx.z;
  int t0 = c * 64;
  size_t hoff = (((size_t)c * 4 + b) * 2048 + d) * 16;
  float An[16], h[16];
#pragma unroll
  for (int n = 0; n < 16; ++n) {
    An[n] = -__expf(A_log[((size_t)d << 4) + n]);
    h[n] = FINAL ? Hin[hoff + n] : 0.f;
  }
  float Dv = FINAL ? Dp[d] : 0.f;
  float dts = 0.f;
  __shared__ float sBC[64][32];
  {
    int s = threadIdx.x >> 2, j8 = (threadIdx.x & 3) * 8;
    size_t rowg = (size_t)b * 2048 + t0 + s;
    uint4 raw = *reinterpret_cast<const uint4*>(dbl + rowg * 128 + 64 + j8);
    unsigned rr4[4] = {raw.x, raw.y, raw.z, raw.w};
#pragma unroll
    for (int q = 0; q < 4; ++q) {
      sBC[s][j8 + 2 * q]     = bf2f((unsigned short)(rr4[q] & 0xffffu));
      sBC[s][j8 + 2 * q + 1] = bf2f((unsigned short)(rr4[q] >> 16));
    }
  }
  __syncthreads();
  for (int si = 0; si < 64; ++si) {
    size_t rr = ((size_t)b * 2048 + t0 + si) * 2048 + d;
    float dtv = dt[rr];
    float uv = bf2f(xc[rr]);
    float dtu = dtv * uv;
    float y = 0.f;
    if constexpr (!FINAL) dts += dtv;
#pragma unroll
    for (int n = 0; n < 16; ++n) {
      float a = __expf(dtv * An[n]);
      h[n] = a * h[n] + dtu * sBC[si][n];
      if constexpr (FINAL) y += h[n] * sBC[si][16 + n];
    }
    if constexpr (FINAL) {
      float zv = bf2f(z[rr]);
      float sig = 1.f / (1.f + __expf(-zv));
      yg[rr] = f2bf((y + Dv * uv) * (zv * sig));
    }
  }
  if constexpr (!FINAL) {
#pragma unroll
    for (int n = 0; n < 16; ++n) S[hoff + n] = h[n];
    SD[((size_t)c * 4 + b) * 2048 + d] = dts;
  }
}

// ---------------- chunk combine, in place: S[c] <- state ENTERING chunk c ----------------
// one thread per (b,d,n) = 131072 threads; reads each S location once then overwrites it.
__global__ __launch_bounds__(256)
void k_scanB(float* __restrict__ S, const float* __restrict__ SD,
             const float* __restrict__ A_log) {
  int id = blockIdx.x * 256 + threadIdx.x;   // B*DI*N
  int n = id & 15, d = (id >> 4) & 2047, b = id >> 15;
  float An = -__expf(A_log[((size_t)d << 4) + n]);
  float h = 0.f;
  for (int c = 0; c < 32; ++c) {
    size_t sdo = ((size_t)c * 4 + b) * 2048 + d;
    size_t o = sdo * 16 + n;
    float s = S[o];
    float p = __expf(An * SD[sdo]);
    S[o] = h;                 // Hin in place
    h = s + p * h;
  }
}

extern "C" void kernel_launch(void* const* d_in, const int* in_sizes, int n_in,
                              void* d_out, int out_size, void* d_ws, size_t ws_size,
                              hipStream_t stream) {
  const float* x       = (const float*)d_in[0];
  const float* ev      = (const float*)d_in[1];
  const float* W_in    = (const float*)d_in[2];
  const float* b_in    = (const float*)d_in[3];
  const float* ln_g    = (const float*)d_in[4];
  const float* ln_b    = (const float*)d_in[5];
  const float* in_proj = (const float*)d_in[6];
  const float* conv_w  = (const float*)d_in[7];
  const float* conv_b  = (const float*)d_in[8];
  const float* x_proj  = (const float*)d_in[9];
  const float* dt_proj = (const float*)d_in[10];
  const float* dt_b    = (const float*)d_in[11];
  const float* A_log   = (const float*)d_in[12];
  const float* D_par   = (const float*)d_in[13];
  const float* out_w   = (const float*)d_in[14];
  float* out = (float*)d_out;

  char* ws = (char*)d_ws;
  size_t off = 0;
  auto alloc = [&](size_t bytes) {
    char* p = ws + off;
    off = (off + bytes + 255) & ~(size_t)255;
    return p;
  };
  float* aug           = (float*)alloc(8192ull * 1024 * 4);   // residual, fp32
  float* dtf           = (float*)alloc(8192ull * 2048 * 4);   // dt after softplus, fp32
  unsigned short* Aaug = (unsigned short*)alloc(8192ull * 1088 * 2);
  unsigned short* WinT = (unsigned short*)alloc(1024ull * 1088 * 2);
  unsigned short* ipT  = (unsigned short*)alloc(4096ull * 1024 * 2);
  unsigned short* xpT  = (unsigned short*)alloc(128ull * 2048 * 2);
  unsigned short* dpT  = (unsigned short*)alloc(2048ull * 64 * 2);
  unsigned short* opT  = (unsigned short*)alloc(1024ull * 2048 * 2);
  unsigned short* xh   = (unsigned short*)alloc(8192ull * 2048 * 2);
  unsigned short* zb   = (unsigned short*)alloc(8192ull * 2048 * 2);
  unsigned short* xcb  = (unsigned short*)alloc(8192ull * 2048 * 2);
  unsigned short* dbl  = (unsigned short*)alloc(8192ull * 128 * 2);
  // scan scratch aliases Aaug (dead after k_gemm<1> consumes hb):
  //   S  = 32*4*2048*16*4 = 16,777,216 B; SD = 32*4*2048*4 = 1,048,576 B; sum == sizeof(Aaug)
  float* Sb = (float*)Aaug;
  float* SD = (float*)((char*)Aaug + 16777216ull);
  unsigned short* hb = Aaug;  // LN output aliases Aaug (consumed by gemm<1> before scan)
  unsigned short* yg = xh;    // gated y aliases xh (consumed by k_conv before scan C)

  k_concat<<<dim3(2, 8192), 256, 0, stream>>>(x, ev, Aaug);
  k_transpose<<<dim3(32, 34), dim3(32, 8), 0, stream>>>(W_in, WinT, 1088, 1024, 1024);
  k_transpose<<<dim3(128, 32), dim3(32, 8), 0, stream>>>(in_proj, ipT, 1024, 4096, 4096);
  k_transpose<<<dim3(4, 64), dim3(32, 8), 0, stream>>>(x_proj, xpT, 2048, 96, 128);
  k_transpose<<<dim3(64, 2), dim3(32, 8), 0, stream>>>(dt_proj, dpT, 64, 2048, 2048);
  k_transpose<<<dim3(32, 64), dim3(32, 8), 0, stream>>>(out_w, opT, 2048, 1024, 1024);

  // aug = [x|ev] @ W_in + b_in   (fp32 out, residual)
  k_gemm<0><<<dim3(8, 64), 256, 0, stream>>>(Aaug, WinT, 1024, 1088, 1088, 1088,
                                             aug, nullptr, nullptr, b_in, nullptr);
  k_ln<<<dim3(8192), 256, 0, stream>>>(aug, ln_g, ln_b, hb);
  // xz = h @ in_proj -> xh | z
  k_gemm<1><<<dim3(32, 64), 256, 0, stream>>>(hb, ipT, 4096, 1024, 1024, 1024,
                                              nullptr, xh, zb, nullptr, nullptr);
  k_conv<<<dim3(8, 2048, 4), 256, 0, stream>>>(xh, conv_w, conv_b, xcb);
  // dbl = xc @ x_proj (N padded 96->128)
  k_gemm<2><<<dim3(1, 64), 256, 0, stream>>>(xcb, xpT, 128, 2048, 2048, 2048,
                                             nullptr, dbl, nullptr, nullptr, nullptr);
  // dt = softplus(dbl[:, :64] @ dt_proj + b)
  k_gemm<3><<<dim3(16, 64), 256, 0, stream>>>(dbl, dpT, 2048, 64, 128, 64,
                                              dtf, nullptr, nullptr, dt_b, nullptr);
  // chunked scan: A (local), B (combine, in place), C (final + gating)
  k_scan<false><<<dim3(8, 4, 32), 256, 0, stream>>>(dtf, xcb, dbl, A_log, Sb, SD,
                                                    nullptr, nullptr, nullptr, nullptr);
  k_scanB<<<dim3(512), 256, 0, stream>>>(Sb, SD, A_log);
  k_scan<true><<<dim3(8, 4, 32), 256, 0, stream>>>(dtf, xcb, dbl, A_log, nullptr, nullptr,
                                                   Sb, D_par, zb, yg);
  // out = residual + yg @ out_proj
  k_gemm<4><<<dim3(8, 64), 256, 0, stream>>>(yg, opT, 1024, 2048, 2048, 2048,
                                             out, nullptr, nullptr, nullptr, aug);
}

// Round 4
// 412.874 us; speedup vs baseline: 1.3100x; 1.1347x over previous
//
#include <hip/hip_runtime.h>
#include <cstdint>
#include <cstddef>

#define DEV __device__ __forceinline__

typedef __bf16 bf16x8 __attribute__((ext_vector_type(8)));
typedef float f32x4 __attribute__((ext_vector_type(4)));

DEV unsigned short f2bf(float f) {
  unsigned u = __builtin_bit_cast(unsigned, f);
  u += 0x7fffu + ((u >> 16) & 1u);   // RNE
  return (unsigned short)(u >> 16);
}
DEV float bf2f(unsigned short h) {
  return __builtin_bit_cast(float, (unsigned)h << 16);
}

// ---------------- concat [x | event] -> bf16 A-matrix [8192 x 1152] (K-padded) ----------------
__global__ __launch_bounds__(256)
void k_concat(const float* __restrict__ x, const float* __restrict__ ev,
              unsigned short* __restrict__ Aaug) {
  int col4 = blockIdx.x * 256 + threadIdx.x;      // float4 index within row, 288 total
  if (col4 >= 288) return;
  size_t row = blockIdx.y;
  float4 v = make_float4(0.f, 0.f, 0.f, 0.f);
  if (col4 < 256)      v = reinterpret_cast<const float4*>(x + row * 1024)[col4];
  else if (col4 < 272) v = reinterpret_cast<const float4*>(ev + row * 64)[col4 - 256];
  ushort4 o; o.x = f2bf(v.x); o.y = f2bf(v.y); o.z = f2bf(v.z); o.w = f2bf(v.w);
  reinterpret_cast<ushort4*>(Aaug + row * 1152)[col4] = o;
}

// ------ tiled transpose fp32[R,C] -> bf16[Cout,Rout] (zero-pad beyond R,C) ------
__global__ void k_transpose(const float* __restrict__ in, unsigned short* __restrict__ out,
                            int R, int C, int Rout, int Cout) {
  __shared__ float tile[32][33];
  int c0 = blockIdx.x * 32, r0 = blockIdx.y * 32;
  int tx = threadIdx.x, ty = threadIdx.y;   // block (32,8)
#pragma unroll
  for (int i = 0; i < 4; ++i) {
    int r = r0 + ty + i * 8, c = c0 + tx;
    tile[ty + i * 8][tx] = (r < R && c < C) ? in[(size_t)r * C + c] : 0.f;
  }
  __syncthreads();
#pragma unroll
  for (int i = 0; i < 4; ++i) {
    int c = c0 + ty + i * 8, r = r0 + tx;
    if (c < Cout && r < Rout) out[(size_t)c * Rout + r] = f2bf(tile[tx][ty + i * 8]);
  }
}

// =====================================================================================
// 8-phase 256xBN MFMA GEMM (T2+T3+T4+T5). A[M,K] bf16 row-major, Bt[N,K] bf16 row-major.
// 512 threads = 8 waves (2M x 4N). BK=64, double-buffered LDS, counted vmcnt.
// stageA halves are MH-ALIGNED: half h = rows {h*64..h*64+63} U {128+h*64..128+h*64+63},
// matching ldA's consumption (ldA(p,mh) reads rows wm*128+mh*64+0..63) so each stage
// only overwrites rows dead since >=1 barrier-pair. (Round-3 bug: contiguous halves
// let P2's stage clobber rows 64..127 still needed by P3's ldA(0,1).)
// EPI 0: outF = acc + bias[col];  EPI 1: split halves -> outB1/outB2 bf16;
// EPI 4: outF = resid + acc.
// =====================================================================================
template <int BN, int EPI>
__global__ __launch_bounds__(512, 2)
void k_gemm8(const unsigned short* __restrict__ A, const unsigned short* __restrict__ Bt,
             int N, int NT, int lda, int ldb,
             float* __restrict__ outF, unsigned short* __restrict__ outB1,
             unsigned short* __restrict__ outB2,
             const float* __restrict__ bias, const float* __restrict__ resid) {
  static_assert(BN == 128 || BN == 256, "");
  constexpr int NF = BN / 64;           // n-frags per wave
  constexpr int NHF = NF / 2;           // n-frags per quadrant
  constexpr int BLOADS = BN / 128;      // global_load_lds per thread per B-half
  constexpr int ATILE = 256 * 64;       // elems
  constexpr int BTILE = BN * 64;
  constexpr int BUFSZ = ATILE + BTILE;
  __shared__ unsigned short lds[2 * BUFSZ];

  const int tid = threadIdx.x;
  const int lane = tid & 63, w = tid >> 6;
  const int wm = w >> 2, wn = w & 3;
  const int frow = lane & 15, fk = lane >> 4;

  const int nbx = gridDim.x;
  const int nwg = nbx * gridDim.y;
  const int orig = blockIdx.y * nbx + blockIdx.x;
  const int swz = (orig & 7) * (nwg >> 3) + (orig >> 3);
  const int brow = swz / nbx, bcol = swz % nbx;
  const size_t row0 = (size_t)brow * 256, col0 = (size_t)bcol * BN;

  f32x4 acc[8][NF];
#pragma unroll
  for (int i = 0; i < 8; ++i)
#pragma unroll
    for (int j = 0; j < NF; ++j) acc[i][j] = f32x4{0.f, 0.f, 0.f, 0.f};

  bf16x8 afr[4][2], bq0[NHF][2], bq1[NHF][2];

  // mh-aligned A halves: for half h, the two 64-row groups l*128 + h*64 (l=0,1)
  auto stageA = [&](int p, int tau, int half) {
    unsigned short* dst = lds + p * BUFSZ + half * 4096 + w * 512;
#pragma unroll
    for (int l = 0; l < 2; ++l) {
      int row = l * 128 + half * 64 + (tid >> 3);
      int g = (tid & 7) ^ (row & 7);
      const unsigned short* src = A + (row0 + row) * lda + tau * 64 + g * 8;
      __builtin_amdgcn_global_load_lds(src, dst + l * 8192, 16, 0, 0);
    }
  };
  auto stageB = [&](int p, int tau, int half) {
    unsigned short* dst = lds + p * BUFSZ + ATILE + half * (BTILE / 2) + w * 512;
#pragma unroll
    for (int l = 0; l < BLOADS; ++l) {
      int row = half * (BN / 2) + l * 64 + (tid >> 3);
      int g = (tid & 7) ^ (row & 7);
      const unsigned short* src = Bt + (col0 + row) * ldb + tau * 64 + g * 8;
      __builtin_amdgcn_global_load_lds(src, dst + l * 4096, 16, 0, 0);
    }
  };
  auto ldA = [&](int p, int mh) {
#pragma unroll
    for (int mi = 0; mi < 4; ++mi)
#pragma unroll
      for (int kb = 0; kb < 2; ++kb) {
        int rr = wm * 128 + mh * 64 + mi * 16 + frow;
        int gk = kb * 4 + fk;
        afr[mi][kb] = *reinterpret_cast<const bf16x8*>(
            lds + p * BUFSZ + rr * 64 + ((gk ^ (rr & 7)) * 8));
      }
  };
  auto ldB = [&](int p, int nh, bf16x8 (&bq)[NHF][2]) {
#pragma unroll
    for (int ni = 0; ni < NHF; ++ni)
#pragma unroll
      for (int kb = 0; kb < 2; ++kb) {
        int cc = wn * (BN / 4) + nh * (BN / 8) + ni * 16 + frow;
        int gk = kb * 4 + fk;
        bq[ni][kb] = *reinterpret_cast<const bf16x8*>(
            lds + p * BUFSZ + ATILE + cc * 64 + ((gk ^ (cc & 7)) * 8));
      }
  };

#define MMAQ(MH, NH, BQ)                                                          \
  do {                                                                            \
    __builtin_amdgcn_s_setprio(1);                                                \
    _Pragma("unroll") for (int mi = 0; mi < 4; ++mi)                              \
        _Pragma("unroll") for (int ni = 0; ni < NHF; ++ni)                        \
            _Pragma("unroll") for (int kb = 0; kb < 2; ++kb)                      \
                acc[(MH)*4 + mi][(NH)*NHF + ni] =                                 \
                    __builtin_amdgcn_mfma_f32_16x16x32_bf16(                      \
                        afr[mi][kb], BQ[ni][kb], acc[(MH)*4 + mi][(NH)*NHF + ni], \
                        0, 0, 0);                                                 \
    __builtin_amdgcn_s_setprio(0);                                                \
  } while (0)

#define BARC  __builtin_amdgcn_s_barrier()
#define SBAR  __builtin_amdgcn_sched_barrier(0)
#define EBAR  do { __builtin_amdgcn_s_barrier(); __builtin_amdgcn_sched_barrier(0); } while (0)
#define VMCNT_WAIT                                                     \
  do {                                                                 \
    if constexpr (BN == 256)                                           \
      asm volatile("s_waitcnt vmcnt(6)" ::: "memory");                 \
    else                                                               \
      asm volatile("s_waitcnt vmcnt(4)" ::: "memory");                 \
  } while (0)

  // ---- prologue: stage buf0=tile0 fully, buf1=tile1 {A.h0,B.h0,B.h1}; drain buf0 ----
  stageA(0, 0, 0); stageB(0, 0, 0); stageB(0, 0, 1); stageA(0, 0, 1);
  SBAR;  // keep buf0-group loads older than buf1-group (vmcnt contract)
  stageA(1, 1, 0); stageB(1, 1, 0); stageB(1, 1, 1);
  VMCNT_WAIT;
  BARC; SBAR;  // pinned: P1's ds_reads must not hoist above this barrier

  const int niter = NT >> 1;
  for (int it = 0; it < niter; ++it) {
    int t = 2 * it;
    int t1s = t + 1;
    int t2s = (t + 2 < NT) ? t + 2 : NT - 1;   // source clamp only; dest parity fixed
    int t3s = (t + 3 < NT) ? t + 3 : NT - 1;
    // P1: quad(0,0) of tile t (buf0); stage buf1.A.h1 (last read prev-P7)
    ldA(0, 0); ldB(0, 0, bq0);
    stageA(1, t1s, 1);
    BARC; MMAQ(0, 0, bq0); EBAR;
    // P2: quad(0,1); stage buf0.A.h0 (rows {0-63,128-191}, last read P1)
    ldB(0, 1, bq1);
    stageA(0, t2s, 0);
    BARC; MMAQ(0, 1, bq1); EBAR;
    // P3: quad(1,1); stage buf0.B.h0 (B dead since P2)
    ldA(0, 1);
    stageB(0, t2s, 0);
    BARC; MMAQ(1, 1, bq1); EBAR;
    // P4: quad(1,0); stage buf0.B.h1; drain buf1=tile t+1
    stageB(0, t2s, 1);
    BARC; MMAQ(1, 0, bq0); VMCNT_WAIT; EBAR;
    // P5: quad(0,0) of tile t+1 (buf1); stage buf0.A.h1 (rows {64-127,192-255}, last read P3)
    ldA(1, 0); ldB(1, 0, bq0);
    stageA(0, t2s, 1);
    BARC; MMAQ(0, 0, bq0); EBAR;
    // P6: quad(0,1); stage buf1.A.h0 (last read P5)
    ldB(1, 1, bq1);
    stageA(1, t3s, 0);
    BARC; MMAQ(0, 1, bq1); EBAR;
    // P7: quad(1,1); stage buf1.B.h0 (B dead since P6)
    ldA(1, 1);
    stageB(1, t3s, 0);
    BARC; MMAQ(1, 1, bq1); EBAR;
    // P8: quad(1,0); stage buf1.B.h1; drain buf0=tile t+2
    stageB(1, t3s, 1);
    BARC; MMAQ(1, 0, bq0); VMCNT_WAIT; EBAR;
  }

#pragma unroll
  for (int q = 0; q < 8; ++q) {
#pragma unroll
    for (int j = 0; j < NF; ++j) {
#pragma unroll
      for (int r = 0; r < 4; ++r) {
        size_t row = row0 + wm * 128 + q * 16 + fk * 4 + r;
        size_t col = col0 + wn * (BN / 4) + j * 16 + frow;
        float v = acc[q][j][r];
        if constexpr (EPI == 0) {
          outF[row * N + col] = v + bias[col];
        } else if constexpr (EPI == 1) {
          int hn = N >> 1;
          if ((int)col < hn) outB1[row * hn + col] = f2bf(v);
          else               outB2[row * hn + (col - hn)] = f2bf(v);
        } else {
          outF[row * N + col] = resid[row * N + col] + v;
        }
      }
    }
  }
#undef MMAQ
#undef BARC
#undef SBAR
#undef EBAR
#undef VMCNT_WAIT
}

// ---------------- 128x128 MFMA GEMM (m97 structure) for the two small GEMMs ----------------
// EPI 2: outB1 bf16, ld = N   (dbl)
// EPI 3: outB1 = bf16(softplus(acc + bias[col]))  (dt)
template <int EPI>
__global__ __launch_bounds__(256)
void k_gemm(const unsigned short* __restrict__ A, const unsigned short* __restrict__ Bt,
            int N, int K, int lda, int ldb,
            unsigned short* __restrict__ outB1, const float* __restrict__ bias) {
  __shared__ alignas(16) unsigned short sA[128 * 64];
  __shared__ alignas(16) unsigned short sB[128 * 64];
  int tid = threadIdx.x;
  int lane = tid & 63, w = tid >> 6;
  int nbx = gridDim.x;
  int nwg = nbx * gridDim.y;
  int orig = blockIdx.y * nbx + blockIdx.x;
  int swz = (orig & 7) * (nwg >> 3) + (orig >> 3);
  int brow = swz / nbx, bcol = swz % nbx;
  size_t row0 = (size_t)brow * 128, col0 = (size_t)bcol * 128;

  int lrow_s = tid >> 3;
  int g_s = tid & 7;
  int wrow = (w >> 1) * 64, wcol = (w & 1) * 64;
  int frow = lane & 15, fk = lane >> 4;
  f32x4 acc[4][4] = {};

  for (int kt = 0; kt < K; kt += 64) {
    __syncthreads();
#pragma unroll
    for (int r = 0; r < 4; ++r) {
      int lr = r * 32 + lrow_s;
      int gs = g_s ^ (lr & 7);
      const unsigned short* srcA = A + (size_t)(row0 + lr) * lda + kt + gs * 8;
      const unsigned short* srcB = Bt + (size_t)(col0 + lr) * ldb + kt + gs * 8;
      unsigned short* dstA = sA + (r * 32 + w * 8) * 64;
      unsigned short* dstB = sB + (r * 32 + w * 8) * 64;
      __builtin_amdgcn_global_load_lds(srcA, dstA, 16, 0, 0);
      __builtin_amdgcn_global_load_lds(srcB, dstB, 16, 0, 0);
    }
    __syncthreads();
#pragma unroll
    for (int kw = 0; kw < 2; ++kw) {
      bf16x8 af[4], bfr[4];
      int gk = kw * 4 + fk;
#pragma unroll
      for (int mi = 0; mi < 4; ++mi) {
        int rr = wrow + mi * 16 + frow;
        af[mi] = *reinterpret_cast<const bf16x8*>(sA + rr * 64 + ((gk ^ (rr & 7)) * 8));
      }
#pragma unroll
      for (int ni = 0; ni < 4; ++ni) {
        int rr = wcol + ni * 16 + frow;
        bfr[ni] = *reinterpret_cast<const bf16x8*>(sB + rr * 64 + ((gk ^ (rr & 7)) * 8));
      }
#pragma unroll
      for (int mi = 0; mi < 4; ++mi)
#pragma unroll
        for (int ni = 0; ni < 4; ++ni)
          acc[mi][ni] = __builtin_amdgcn_mfma_f32_16x16x32_bf16(af[mi], bfr[ni], acc[mi][ni], 0, 0, 0);
    }
  }

#pragma unroll
  for (int mi = 0; mi < 4; ++mi) {
#pragma unroll
    for (int ni = 0; ni < 4; ++ni) {
#pragma unroll
      for (int r = 0; r < 4; ++r) {
        size_t row = row0 + wrow + mi * 16 + fk * 4 + r;
        size_t col = col0 + wcol + ni * 16 + frow;
        float v = acc[mi][ni][r];
        if constexpr (EPI == 2) {
          outB1[row * N + col] = f2bf(v);
        } else {
          float xx = v + bias[col];
          float sp = (xx > 15.f) ? xx : __logf(1.f + __expf(xx));
          outB1[row * N + col] = f2bf(sp);
        }
      }
    }
  }
}

// ---------------- LayerNorm over D=1024, fp32 in -> bf16 out ----------------
__global__ __launch_bounds__(256)
void k_ln(const float* __restrict__ aug, const float* __restrict__ gam,
          const float* __restrict__ bet, unsigned short* __restrict__ h) {
  int tid = threadIdx.x;
  size_t row = blockIdx.x;
  float4 v = reinterpret_cast<const float4*>(aug + row * 1024)[tid];
  float s = v.x + v.y + v.z + v.w;
  float ss = v.x * v.x + v.y * v.y + v.z * v.z + v.w * v.w;
#pragma unroll
  for (int m = 32; m >= 1; m >>= 1) {
    s += __shfl_xor(s, m, 64);
    ss += __shfl_xor(ss, m, 64);
  }
  __shared__ float rb[8];
  if ((tid & 63) == 0) { rb[tid >> 6] = s; rb[4 + (tid >> 6)] = ss; }
  __syncthreads();
  float ts = rb[0] + rb[1] + rb[2] + rb[3];
  float tss = rb[4] + rb[5] + rb[6] + rb[7];
  float mu = ts * (1.f / 1024.f);
  float var = tss * (1.f / 1024.f) - mu * mu;
  float rs = rsqrtf(var + 1e-5f);
  float4 gv = reinterpret_cast<const float4*>(gam)[tid];
  float4 bv = reinterpret_cast<const float4*>(bet)[tid];
  ushort4 o;
  o.x = f2bf((v.x - mu) * rs * gv.x + bv.x);
  o.y = f2bf((v.y - mu) * rs * gv.y + bv.y);
  o.z = f2bf((v.z - mu) * rs * gv.z + bv.z);
  o.w = f2bf((v.w - mu) * rs * gv.w + bv.w);
  reinterpret_cast<ushort4*>(h + row * 1024)[tid] = o;
}

// ---------------- causal depthwise conv (K=4) + SiLU ----------------
__global__ __launch_bounds__(256)
void k_conv(const unsigned short* __restrict__ xh, const float* __restrict__ cw,
            const float* __restrict__ cb, unsigned short* __restrict__ xc) {
  int d = blockIdx.x * 256 + threadIdx.x;     // 2048
  int t = blockIdx.y, b = blockIdx.z;
  size_t rowb = (size_t)b * 2048;             // b*L
  float acc = cb[d];
#pragma unroll
  for (int k = 0; k < 4; ++k) {
    int tt = t - 3 + k;
    if (tt >= 0) acc += cw[d * 4 + k] * bf2f(xh[(rowb + tt) * 2048 + d]);
  }
  float sg = 1.f / (1.f + __expf(-acc));
  xc[(rowb + t) * 2048 + d] = f2bf(acc * sg);
}

// ---------------- chunked selective scan: 64 chunks x 32 steps ----------------
// Pass A (FINAL=false): local state S (from h=0) and per-chunk sum of dt (SD).
// Pass C (FINAL=true): init from Hin, produce y, fuse +D*u and *silu(z).
// Fast path exploits A[d][n] = -(n+1): exp(dt*A[n]) = exp(-dt)^(n+1) (power chain),
// with a runtime-verified fallback to the general exp form.
template <bool FINAL>
__global__ __launch_bounds__(256)
void k_scan(const unsigned short* __restrict__ dt, const unsigned short* __restrict__ xc,
            const unsigned short* __restrict__ dbl, const float* __restrict__ A_log,
            float* __restrict__ S, float* __restrict__ SD,
            const float* __restrict__ Hin, const float* __restrict__ Dp,
            const unsigned short* __restrict__ z, unsigned short* __restrict__ yg) {
  int d = blockIdx.x * 256 + threadIdx.x;
  int b = blockIdx.y, c = blockIdx.z;        // c in 0..63
  int t0 = c * 32;
  size_t hoff = (((size_t)c * 4 + b) * 2048 + d) * 16;
  float An[16], h[16];
  bool fast = true;
#pragma unroll
  for (int n = 0; n < 16; ++n) {
    An[n] = -__expf(A_log[((size_t)d << 4) + n]);
    fast = fast && (__builtin_fabsf(An[n] + (float)(n + 1)) < 1e-4f);
    h[n] = FINAL ? Hin[hoff + n] : 0.f;
  }
  float Dv = FINAL ? Dp[d] : 0.f;
  float dts = 0.f;
  __shared__ float sBC[32][32];
  if (threadIdx.x < 128) {
    int s = threadIdx.x >> 2, j8 = (threadIdx.x & 3) * 8;
    size_t rowg = (size_t)b * 2048 + t0 + s;
    uint4 raw = *reinterpret_cast<const uint4*>(dbl + rowg * 128 + 64 + j8);
    unsigned rr4[4] = {raw.x, raw.y, raw.z, raw.w};
#pragma unroll
    for (int q = 0; q < 4; ++q) {
      sBC[s][j8 + 2 * q]     = bf2f((unsigned short)(rr4[q] & 0xffffu));
      sBC[s][j8 + 2 * q + 1] = bf2f((unsigned short)(rr4[q] >> 16));
    }
  }
  __syncthreads();

  if (fast) {
    for (int si = 0; si < 32; ++si) {
      size_t rr = ((size_t)b * 2048 + t0 + si) * 2048 + d;
      float dtv = bf2f(dt[rr]);
      float uv = bf2f(xc[rr]);
      float dtu = dtv * uv;
      float y = 0.f;
      if constexpr (!FINAL) dts += dtv;
      float e1 = __expf(-dtv);
      float a = e1;
#pragma unroll
      for (int n = 0; n < 16; ++n) {
        h[n] = a * h[n] + dtu * sBC[si][n];
        if constexpr (FINAL) y += h[n] * sBC[si][16 + n];
        a *= e1;
      }
      if constexpr (FINAL) {
        float zv = bf2f(z[rr]);
        float sig = 1.f / (1.f + __expf(-zv));
        yg[rr] = f2bf((y + Dv * uv) * (zv * sig));
      }
    }
  } else {
    for (int si = 0; si < 32; ++si) {
      size_t rr = ((size_t)b * 2048 + t0 + si) * 2048 + d;
      float dtv = bf2f(dt[rr]);
      float uv = bf2f(xc[rr]);
      float dtu = dtv * uv;
      float y = 0.f;
      if constexpr (!FINAL) dts += dtv;
#pragma unroll
      for (int n = 0; n < 16; ++n) {
        float a = __expf(dtv * An[n]);
        h[n] = a * h[n] + dtu * sBC[si][n];
        if constexpr (FINAL) y += h[n] * sBC[si][16 + n];
      }
      if constexpr (FINAL) {
        float zv = bf2f(z[rr]);
        float sig = 1.f / (1.f + __expf(-zv));
        yg[rr] = f2bf((y + Dv * uv) * (zv * sig));
      }
    }
  }
  if constexpr (!FINAL) {
#pragma unroll
    for (int n = 0; n < 16; ++n) S[hoff + n] = h[n];
    SD[((size_t)c * 4 + b) * 2048 + d] = dts;
  }
}

// ---------------- chunk combine, in place: S[c] <- state ENTERING chunk c ----------------
__global__ __launch_bounds__(256)
void k_scanB(float* __restrict__ S, const float* __restrict__ SD,
             const float* __restrict__ A_log) {
  int id = blockIdx.x * 256 + threadIdx.x;   // B*DI*N = 131072
  int n = id & 15, d = (id >> 4) & 2047, b = id >> 15;
  float An = -__expf(A_log[((size_t)d << 4) + n]);
  float h = 0.f;
  for (int c = 0; c < 64; ++c) {
    size_t sdo = ((size_t)c * 4 + b) * 2048 + d;
    size_t o = sdo * 16 + n;
    float s = S[o];
    float p = __expf(An * SD[sdo]);
    S[o] = h;                 // Hin in place
    h = s + p * h;
  }
}

extern "C" void kernel_launch(void* const* d_in, const int* in_sizes, int n_in,
                              void* d_out, int out_size, void* d_ws, size_t ws_size,
                              hipStream_t stream) {
  const float* x       = (const float*)d_in[0];
  const float* ev      = (const float*)d_in[1];
  const float* W_in    = (const float*)d_in[2];
  const float* b_in    = (const float*)d_in[3];
  const float* ln_g    = (const float*)d_in[4];
  const float* ln_b    = (const float*)d_in[5];
  const float* in_proj = (const float*)d_in[6];
  const float* conv_w  = (const float*)d_in[7];
  const float* conv_b  = (const float*)d_in[8];
  const float* x_proj  = (const float*)d_in[9];
  const float* dt_proj = (const float*)d_in[10];
  const float* dt_b    = (const float*)d_in[11];
  const float* A_log   = (const float*)d_in[12];
  const float* D_par   = (const float*)d_in[13];
  const float* out_w   = (const float*)d_in[14];
  float* out = (float*)d_out;

  char* ws = (char*)d_ws;
  size_t off = 0;
  auto alloc = [&](size_t bytes) {
    char* p = ws + off;
    off = (off + bytes + 255) & ~(size_t)255;
    return p;
  };
  float* aug            = (float*)alloc(8192ull * 1024 * 4);    // residual, fp32
  unsigned short* dtfb  = (unsigned short*)alloc(8192ull * 2048 * 2);  // dt (softplus), bf16
  unsigned short* Aaug  = (unsigned short*)alloc(8192ull * 1152 * 2);  // K padded to 1152
  unsigned short* WinT  = (unsigned short*)alloc(1024ull * 1152 * 2);
  unsigned short* ipT   = (unsigned short*)alloc(4096ull * 1024 * 2);
  unsigned short* xpT   = (unsigned short*)alloc(128ull * 2048 * 2);
  unsigned short* dpT   = (unsigned short*)alloc(2048ull * 64 * 2);
  unsigned short* opT   = (unsigned short*)alloc(1024ull * 2048 * 2);
  unsigned short* xh    = (unsigned short*)alloc(8192ull * 2048 * 2);
  unsigned short* zb    = (unsigned short*)alloc(8192ull * 2048 * 2);
  unsigned short* xcb   = (unsigned short*)alloc(8192ull * 2048 * 2);
  unsigned short* dbl   = (unsigned short*)alloc(8192ull * 128 * 2);
  float* Sb = (float*)alloc(64ull * 4 * 2048 * 16 * 4);
  float* SD = (float*)alloc(64ull * 4 * 2048 * 4);
  unsigned short* hb = Aaug;  // LN output aliases Aaug (Aaug dead after gemm8<0>)
  unsigned short* yg = xh;    // gated y aliases xh (xh dead after k_conv)

  k_concat<<<dim3(2, 8192), 256, 0, stream>>>(x, ev, Aaug);
  k_transpose<<<dim3(32, 36), dim3(32, 8), 0, stream>>>(W_in, WinT, 1088, 1024, 1152, 1024);
  k_transpose<<<dim3(128, 32), dim3(32, 8), 0, stream>>>(in_proj, ipT, 1024, 4096, 1024, 4096);
  k_transpose<<<dim3(4, 64), dim3(32, 8), 0, stream>>>(x_proj, xpT, 2048, 96, 2048, 128);
  k_transpose<<<dim3(64, 2), dim3(32, 8), 0, stream>>>(dt_proj, dpT, 64, 2048, 64, 2048);
  k_transpose<<<dim3(32, 64), dim3(32, 8), 0, stream>>>(out_w, opT, 2048, 1024, 2048, 1024);

  // aug = [x|ev] @ W_in + b_in   (fp32 out, residual); K 1088 padded to 1152 (NT=18)
  k_gemm8<128, 0><<<dim3(8, 32), 512, 0, stream>>>(Aaug, WinT, 1024, 18, 1152, 1152,
                                                   aug, nullptr, nullptr, b_in, nullptr);
  k_ln<<<dim3(8192), 256, 0, stream>>>(aug, ln_g, ln_b, hb);
  // xz = h @ in_proj -> xh | z   (NT=16)
  k_gemm8<256, 1><<<dim3(16, 32), 512, 0, stream>>>(hb, ipT, 4096, 16, 1024, 1024,
                                                    nullptr, xh, zb, nullptr, nullptr);
  k_conv<<<dim3(8, 2048, 4), 256, 0, stream>>>(xh, conv_w, conv_b, xcb);
  // dbl = xc @ x_proj (N padded 96->128)
  k_gemm<2><<<dim3(1, 64), 256, 0, stream>>>(xcb, xpT, 128, 2048, 2048, 2048, dbl, nullptr);
  // dt = softplus(dbl[:, :64] @ dt_proj + b) -> bf16
  k_gemm<3><<<dim3(16, 64), 256, 0, stream>>>(dbl, dpT, 2048, 64, 128, 64, dtfb, dt_b);
  // chunked scan: A (local), B (combine, in place), C (final + gating)
  k_scan<false><<<dim3(8, 4, 64), 256, 0, stream>>>(dtfb, xcb, dbl, A_log, Sb, SD,
                                                    nullptr, nullptr, nullptr, nullptr);
  k_scanB<<<dim3(512), 256, 0, stream>>>(Sb, SD, A_log);
  k_scan<true><<<dim3(8, 4, 64), 256, 0, stream>>>(dtfb, xcb, dbl, A_log, nullptr, nullptr,
                                                   Sb, D_par, zb, yg);
  // out = residual + yg @ out_proj   (NT=32)
  k_gemm8<128, 4><<<dim3(8, 32), 512, 0, stream>>>(yg, opT, 1024, 32, 2048, 2048,
                                                   out, nullptr, nullptr, nullptr, aug);
}